// Round 5
// baseline (882.170 us; speedup 1.0000x reference)
//
#include <hip/hip_runtime.h>
#include <stdint.h>
#include <math.h>

#define NB 16384      // batch
#define NSEQ 32       // sequence length
#define NV 1001       // vocab (V+1)
#define NROWS 32768   // 2 * NB flattened rows

typedef float v2f __attribute__((ext_vector_type(2)));

// ---------------- threefry2x32 (JAX-exact) ----------------
__device__ __forceinline__ void tf2x32(uint32_t k0, uint32_t k1,
                                       uint32_t x0, uint32_t x1,
                                       uint32_t& o0, uint32_t& o1) {
  const uint32_t ks0 = k0, ks1 = k1, ks2 = k0 ^ k1 ^ 0x1BD11BDAu;
  x0 += ks0; x1 += ks1;
  const int rA[4] = {13, 15, 26, 6};
  const int rB[4] = {17, 29, 16, 24};
#pragma unroll
  for (int i = 0; i < 4; ++i) { x0 += x1; x1 = (x1 << rA[i]) | (x1 >> (32 - rA[i])); x1 ^= x0; }
  x0 += ks1; x1 += ks2 + 1u;
#pragma unroll
  for (int i = 0; i < 4; ++i) { x0 += x1; x1 = (x1 << rB[i]) | (x1 >> (32 - rB[i])); x1 ^= x0; }
  x0 += ks2; x1 += ks0 + 2u;
#pragma unroll
  for (int i = 0; i < 4; ++i) { x0 += x1; x1 = (x1 << rA[i]) | (x1 >> (32 - rA[i])); x1 ^= x0; }
  x0 += ks0; x1 += ks1 + 3u;
#pragma unroll
  for (int i = 0; i < 4; ++i) { x0 += x1; x1 = (x1 << rB[i]) | (x1 >> (32 - rB[i])); x1 ^= x0; }
  x0 += ks1; x1 += ks2 + 4u;
#pragma unroll
  for (int i = 0; i < 4; ++i) { x0 += x1; x1 = (x1 << rA[i]) | (x1 >> (32 - rA[i])); x1 ^= x0; }
  o0 = x0 + ks2; o1 = x1 + ks0 + 5u;
}

__device__ __forceinline__ float gumbel_from_bits(uint32_t bits) {
  uint32_t fb = (bits >> 9) | 0x3f800000u;
  float u = __uint_as_float(fb) - 1.0f;
  u = fmaxf(u, 1.17549435e-38f);
  return -logf(-logf(u));
}

__device__ __forceinline__ float sigm(float x) { return 1.0f / (1.0f + __expf(-x)); }
__device__ __forceinline__ float tanh_(float x) {
  float e = __expf(2.0f * x);
  return 1.0f - 2.0f / (e + 1.0f);
}

__device__ __forceinline__ float dot64(const float* __restrict__ w, const float* h) {
  float a = 0.f;
#pragma unroll
  for (int k = 0; k < 64; ++k) a = fmaf(w[k], h[k], a);
  return a;
}

// Team-of-4 categorical sample + logprob. Lane g owns candidates c = g + 4*i.
template <int N>
__device__ __forceinline__ void samp_team(const float* lg, int g, int C,
                                          uint32_t k0, uint32_t k1, int b,
                                          int& sOut, float& lpOut) {
  float m = -__builtin_inff();
#pragma unroll
  for (int i = 0; i < N; ++i) m = fmaxf(m, lg[i]);
  m = fmaxf(m, __shfl_xor(m, 1));
  m = fmaxf(m, __shfl_xor(m, 2));
  float se = 0.f;
#pragma unroll
  for (int i = 0; i < N; ++i) se += expf(lg[i] - m);
  se += __shfl_xor(se, 1);
  se += __shfl_xor(se, 2);
  const float lse = logf(se);
  float bz = -__builtin_inff(), bl = 0.f;
  int bi = 0x7fffffff;
#pragma unroll
  for (int i = 0; i < N; ++i) {
    const int c = g + 4 * i;
    uint32_t o0, o1; tf2x32(k0, k1, 0u, (uint32_t)(b * C + c), o0, o1);
    const float z = lg[i] + gumbel_from_bits(o0 ^ o1);
    if (z > bz || (z == bz && c < bi)) { bz = z; bi = c; bl = lg[i]; }
  }
#pragma unroll
  for (int d = 1; d <= 2; d <<= 1) {
    const float z2 = __shfl_xor(bz, d);
    const int i2 = __shfl_xor(bi, d);
    const float l2 = __shfl_xor(bl, d);
    if (z2 > bz || (z2 == bz && i2 < bi)) { bz = z2; bi = i2; bl = l2; }
  }
  sOut = bi;
  lpOut = (bl - m) - lse;
}

// ---------------- kernel A: embedW precompute ----------------
// embedW[v][j] = b_ih[j] + b_hh[j] + sum_k embed[v][k]*W_ih[j][k]
__global__ __launch_bounds__(256) void k_prep(
    const float* __restrict__ embed, const float* __restrict__ W_ih,
    const float* __restrict__ b_ih, const float* __restrict__ b_hh,
    float* __restrict__ embedW) {
  __shared__ float er[64];
  int v = blockIdx.x;
  if (threadIdx.x < 64) er[threadIdx.x] = embed[v * 64 + threadIdx.x];
  __syncthreads();
  int j = threadIdx.x;
  float a = b_ih[j] + b_hh[j];
#pragma unroll
  for (int k = 0; k < 64; ++k) a = fmaf(W_ih[j * 64 + k], er[k], a);
  embedW[v * 256 + j] = a;
}

// ---------------- kernel B: LSTM, resident-weight / readlane-broadcast ------
// 256 WGs x 512 thr (1 WG/CU, 2 waves/SIMD). Lane = hidden unit j.
// Wave = gatepair gp (0:(i,f), 1:(g,o)) x row-quarter rq (32 rows each).
// Lane j holds PACKED weights w2[k] = {W[2gp*64+j][k], W[(2gp+1)*64+j][k]}
// resident in 128 VGPRs for all 32 steps -> zero per-step weight traffic
// (r4's LDS-broadcast cost: 49k cyc/CU/step, the 3.4x-over-floor limiter).
// h broadcast per (row,k): v_readlane -> SGPR -> v_pk_fma_f32 (2 gates/instr).
// LDS: 5 fixed 32KB regions (h,i,f,g,o) = 160 KB -> all gate writes eager,
// 2 barriers/step. Update phase: 16 cells/thread, c resident in regs.
__global__ __launch_bounds__(512, 2) void k_lstm(
    const int* __restrict__ inst0, const int* __restrict__ inst1,
    const float* __restrict__ embedW, const float* __restrict__ W_hh,
    float* __restrict__ hT) {
  extern __shared__ float sm[];
  float* Rh = sm;            // h_t  [128 row][64 unit]
  float* Ri = sm + 8192;
  float* Rf = sm + 16384;
  float* Rg = sm + 24576;
  float* Ro = sm + 32768;

  const int tid = threadIdx.x;
  const int lane = tid & 63;
  const int wave = tid >> 6;       // 0..7
  const int gp = wave >> 2;        // 0:(i,f)  1:(g,o)
  const int rq = wave & 3;
  const int wrow = rq * 32;
  const int blk = blockIdx.x;

  // resident packed weights (one-time load, L2-hot after first waves)
  v2f w2[64];
  {
    const float* wl = W_hh + (gp * 128 + lane) * 64;
    const float* wh = W_hh + (gp * 128 + 64 + lane) * 64;
#pragma unroll
    for (int c4 = 0; c4 < 16; ++c4) {
      const float4 lo = *(const float4*)(wl + c4 * 4);
      const float4 hi = *(const float4*)(wh + c4 * 4);
      w2[c4 * 4 + 0] = (v2f){lo.x, hi.x};
      w2[c4 * 4 + 1] = (v2f){lo.y, hi.y};
      w2[c4 * 4 + 2] = (v2f){lo.z, hi.z};
      w2[c4 * 4 + 3] = (v2f){lo.w, hi.w};
    }
  }

  for (int i = tid; i < 8192; i += 512) Rh[i] = 0.f;
  float c[16];
#pragma unroll
  for (int i = 0; i < 16; ++i) c[i] = 0.f;

  // lanes 0..31 map to this wave's 32 rows (vocab-id vector for readlane)
  const int flatrow = blk * 128 + wrow + (lane & 31);
  const int* __restrict__ inst = (blk < 128) ? inst0 : inst1;
  const int bb = flatrow & (NB - 1);
  __syncthreads();

#pragma unroll 1
  for (int t = 0; t < NSEQ; ++t) {
    const int vvt = inst[bb * NSEQ + t];
    float hvc0 = Rh[(wrow + 0) * 64 + lane];
    float hvc1 = Rh[(wrow + 1) * 64 + lane];
#pragma unroll 1
    for (int r2 = 0; r2 < 16; ++r2) {
      const int r0_ = 2 * r2, r1_ = r0_ + 1;
      float hvn0 = 0.f, hvn1 = 0.f;
      if (r2 < 15) {  // prefetch next pair's h vectors (hide ds_read latency)
        hvn0 = Rh[(wrow + r0_ + 2) * 64 + lane];
        hvn1 = Rh[(wrow + r1_ + 2) * 64 + lane];
      }
      const int va = __builtin_amdgcn_readlane(vvt, r0_);
      const int vb = __builtin_amdgcn_readlane(vvt, r1_);
      const float* ea = embedW + va * 256 + gp * 128 + lane;
      const float* eb = embedW + vb * 256 + gp * 128 + lane;
      const float ea0 = ea[0], ea1 = ea[64];   // consumed after k-loop
      const float eb0 = eb[0], eb1 = eb[64];
      v2f a0 = {0.f, 0.f}, a1 = {0.f, 0.f};
#pragma unroll
      for (int k = 0; k < 64; ++k) {
        const float s0 = __int_as_float(__builtin_amdgcn_readlane(__float_as_int(hvc0), k));
        const float s1 = __int_as_float(__builtin_amdgcn_readlane(__float_as_int(hvc1), k));
        a0 = __builtin_elementwise_fma(w2[k], (v2f){s0, s0}, a0);
        a1 = __builtin_elementwise_fma(w2[k], (v2f){s1, s1}, a1);
      }
      a0 += (v2f){ea0, ea1};
      a1 += (v2f){eb0, eb1};
      const int cell0 = (wrow + r0_) * 64 + lane;
      const int cell1 = (wrow + r1_) * 64 + lane;
      if (gp == 0) {
        Ri[cell0] = a0.x; Rf[cell0] = a0.y;
        Ri[cell1] = a1.x; Rf[cell1] = a1.y;
      } else {
        Rg[cell0] = a0.x; Ro[cell0] = a0.y;
        Rg[cell1] = a1.x; Ro[cell1] = a1.y;
      }
      hvc0 = hvn0; hvc1 = hvn1;
    }
    __syncthreads();   // gates complete
#pragma unroll
    for (int i = 0; i < 16; ++i) {
      const int ad = (i * 8 + wave) * 64 + lane;
      const float gi = Ri[ad], gf = Rf[ad], gg = Rg[ad], go = Ro[ad];
      const float ci = sigm(gf) * c[i] + sigm(gi) * tanh_(gg);
      c[i] = ci;
      Rh[ad] = sigm(go) * tanh_(ci);   // h_{t+1}; old h dead
    }
    __syncthreads();   // h_{t+1} visible
  }

  // transposed store: hT[u][flat] (one-time; LDS conflicts tolerable)
#pragma unroll
  for (int i = 0; i < 8; ++i) {
#pragma unroll
    for (int hf = 0; hf < 2; ++hf) {
      hT[(wave * 8 + i) * NROWS + blk * 128 + hf * 64 + lane] =
          Rh[(hf * 64 + lane) * 64 + wave * 8 + i];
    }
  }
}

// ---------------- kernel C: heads, 4-lane team per row (bit-exact r3) ------
__global__ __launch_bounds__(256) void k_heads(
    const int* __restrict__ canvas0, const int* __restrict__ canvas1,
    const int* __restrict__ ref,
    const float* __restrict__ Wc, const float* __restrict__ bc,
    const float* __restrict__ Ws, const float* __restrict__ bs,
    const float* __restrict__ Wl, const float* __restrict__ bl,
    const float* __restrict__ Wr1, const float* __restrict__ br1,
    const float* __restrict__ Wr2, const float* __restrict__ br2,
    const float* __restrict__ Wp, const float* __restrict__ bp,
    const float* __restrict__ hT, float* __restrict__ out) {
  const int tid = threadIdx.x;
  const int g = tid & 3;
  const int s = blockIdx.x & 1;
  const int b = (blockIdx.x >> 1) * 64 + (tid >> 2);
  const float NEG = -__builtin_inff();

  uint32_t kk0[7], kk1[7];
#pragma unroll
  for (int i = 0; i < 7; ++i) {
    uint32_t o0, o1; tf2x32(0u, 42u, 0u, (uint32_t)i, o0, o1);
    kk0[i] = o0; kk1[i] = o1;
  }

  float h[64];
#pragma unroll
  for (int u = 0; u < 64; ++u) h[u] = hT[u * NROWS + s * NB + b];

  float lgc[1], lgs[1];
  lgc[0] = (g < 3) ? (bc[g] + dot64(Wc + g * 64, h)) : NEG;
  lgs[0] = (g < 3) ? (bs[g] + dot64(Ws + g * 64, h)) : NEG;

  if (s == 0) {
    int cs0, ss0, loc0; float clp0, slp0, llp0;
    samp_team<1>(lgc, g, 3, kk0[0], kk1[0], b, cs0, clp0);
    samp_team<1>(lgs, g, 3, kk0[1], kk1[1], b, ss0, slp0);
    float lgl[7];
#pragma unroll
    for (int i = 0; i < 7; ++i) {
      const int cc = g + 4 * i;
      lgl[i] = (cc < 25) ? (bl[cc] + dot64(Wl + cc * 64, h)) : NEG;
    }
    samp_team<7>(lgl, g, 25, kk0[2], kk1[2], b, loc0, llp0);

    if (g == 0) {
      const int p0 = min(max(loc0, 0), 24);
      const int4 pt = ((const int4*)(canvas1 + b * 100))[p0];
      const bool ok0 = (loc0 >= 0) && (loc0 < 25) && (pt.x + pt.y + pt.z + pt.w >= 0);
      const float loc_r0 = ok0 ? 1.f : -1.f;
      const float col_r0 = ok0 ? ((cs0 == pt.x) ? 1.f : -1.f) : 0.f;
      out[0 * NB + b] = clp0;
      out[1 * NB + b] = slp0;
      out[2 * NB + b] = llp0;
      out[7 * NB + b] = loc_r0;
      out[8 * NB + b] = col_r0;
      out[9 * NB + b] = loc_r0;
    }
  } else {
    int cs1, ss1, ls1; float clp1, slp1, llp1;
    samp_team<1>(lgc, g, 3, kk0[3], kk1[3], b, cs1, clp1);
    samp_team<1>(lgs, g, 3, kk0[4], kk1[4], b, ss1, slp1);
    float lgp[2];
#pragma unroll
    for (int i = 0; i < 2; ++i) {
      const int cc = g + 4 * i;
      lgp[i] = bp[cc] + dot64(Wp + cc * 64, h);
    }
    samp_team<2>(lgp, g, 8, kk0[5], kk1[5], b, ls1, llp1);

    float uv8[8], w64[8], w65[8], w66[8], w67[8], wr2[8];
#pragma unroll
    for (int i = 0; i < 8; ++i) {
      const int j = g + 4 * i;
      uv8[i] = br1[j] + dot64(Wr1 + j * 68, h);
      const float* wr = Wr1 + j * 68 + 64;
      w64[i] = wr[0]; w65[i] = wr[1]; w66[i] = wr[2]; w67[i] = wr[3];
      wr2[i] = Wr2[j];
    }
    float lgA[7];
#pragma unroll
    for (int i = 0; i < 7; ++i) lgA[i] = NEG;
    const float b2 = br2[0];
#pragma unroll
    for (int p = 0; p < 25; ++p) {
      const int4 c4 = ((const int4*)(canvas0 + b * 100))[p];
      const float f0 = (float)c4.x, f1 = (float)c4.y;
      const float f2 = (float)c4.z, f3 = (float)c4.w;
      float part = 0.f;
#pragma unroll
      for (int i = 0; i < 8; ++i) {
        float hj = uv8[i];
        hj = fmaf(w64[i], f0, hj);
        hj = fmaf(w65[i], f1, hj);
        hj = fmaf(w66[i], f2, hj);
        hj = fmaf(w67[i], f3, hj);
        part = fmaf(wr2[i], fmaxf(hj, 0.f), part);
      }
      part += __shfl_xor(part, 1);
      part += __shfl_xor(part, 2);
      const float ap = b2 + part;
      if ((p & 3) == g) lgA[p >> 2] = ap;
    }
    int att_s; float alp1;
    samp_team<7>(lgA, g, 25, kk0[6], kk1[6], b, att_s, alp1);

    if (g == 0) {
      const int4 r4 = ((const int4*)(canvas0 + b * 100))[att_s];
      const int4 rr = *(const int4*)(ref + b * 4);
      const bool match = (r4.x == rr.x) && (r4.y == rr.y) &&
                         (r4.z == rr.z) && (r4.w == rr.w);
      const float att_reward = match ? 1.f : -1.f;
      const int ox = (int)((0x22001120u >> (ls1 * 4)) & 0xFu) - 1;
      const int oy = (int)((0x20200211u >> (ls1 * 4)) & 0xFu) - 1;
      const int loc1 = (r4.z + ox) * 5 + (r4.w + oy);
      const int p1 = min(max(loc1, 0), 24);
      const int4 q4 = ((const int4*)(canvas1 + b * 100))[p1];
      const bool ok1 = (loc1 >= 0) && (loc1 < 25) && (q4.x + q4.y + q4.z + q4.w >= 0);
      const float loc_r1 = ok1 ? 1.f : -1.f;
      const float col_r1 = ok1 ? ((cs1 == q4.x) ? 1.f : -1.f) : 0.f;
      out[3 * NB + b]  = clp1;
      out[4 * NB + b]  = slp1;
      out[5 * NB + b]  = llp1;
      out[6 * NB + b]  = alp1;
      out[10 * NB + b] = loc_r1;
      out[11 * NB + b] = col_r1;
      out[12 * NB + b] = loc_r1;
      out[13 * NB + b] = att_reward;
    }
  }
}

extern "C" void kernel_launch(void* const* d_in, const int* in_sizes, int n_in,
                              void* d_out, int out_size, void* d_ws, size_t ws_size,
                              hipStream_t stream) {
  const int* inst0 = (const int*)d_in[0];
  const int* inst1 = (const int*)d_in[1];
  const int* canvas0 = (const int*)d_in[2];
  const int* canvas1 = (const int*)d_in[3];
  const int* ref = (const int*)d_in[4];
  const float* embed = (const float*)d_in[5];
  const float* W_ih = (const float*)d_in[6];
  const float* W_hh = (const float*)d_in[7];
  const float* b_ih = (const float*)d_in[8];
  const float* b_hh = (const float*)d_in[9];
  const float* Wc = (const float*)d_in[10];
  const float* bc = (const float*)d_in[11];
  const float* Ws = (const float*)d_in[12];
  const float* bs = (const float*)d_in[13];
  const float* Wl = (const float*)d_in[14];
  const float* bl = (const float*)d_in[15];
  const float* Wr1 = (const float*)d_in[16];
  const float* br1 = (const float*)d_in[17];
  const float* Wr2 = (const float*)d_in[18];
  const float* br2 = (const float*)d_in[19];
  const float* Wp = (const float*)d_in[20];
  const float* bp = (const float*)d_in[21];

  float* ws = (float*)d_ws;
  float* embedW = ws;                    // 1001*256
  float* hT = embedW + NV * 256;         // 64*32768
  float* out = (float*)d_out;

  // opt in to 160 KB dynamic LDS (idempotent, host-side, capture-safe)
  (void)hipFuncSetAttribute((const void*)k_lstm,
                            hipFuncAttributeMaxDynamicSharedMemorySize, 163840);

  k_prep<<<NV, 256, 0, stream>>>(embed, W_ih, b_ih, b_hh, embedW);
  k_lstm<<<256, 512, 163840, stream>>>(inst0, inst1, embedW, W_hh, hT);
  k_heads<<<512, 256, 0, stream>>>(canvas0, canvas1, ref, Wc, bc, Ws, bs,
                                   Wl, bl, Wr1, br1, Wr2, br2, Wp, bp, hT, out);
}

// Round 6
// 825.807 us; speedup vs baseline: 1.0683x; 1.0683x over previous
//
#include <hip/hip_runtime.h>
#include <stdint.h>
#include <math.h>

#define NB 16384      // batch
#define NSEQ 32       // sequence length
#define NV 1001       // vocab (V+1)
#define NROWS 32768   // 2 * NB flattened rows

// ---------------- threefry2x32 (JAX-exact) ----------------
__device__ __forceinline__ void tf2x32(uint32_t k0, uint32_t k1,
                                       uint32_t x0, uint32_t x1,
                                       uint32_t& o0, uint32_t& o1) {
  const uint32_t ks0 = k0, ks1 = k1, ks2 = k0 ^ k1 ^ 0x1BD11BDAu;
  x0 += ks0; x1 += ks1;
  const int rA[4] = {13, 15, 26, 6};
  const int rB[4] = {17, 29, 16, 24};
#pragma unroll
  for (int i = 0; i < 4; ++i) { x0 += x1; x1 = (x1 << rA[i]) | (x1 >> (32 - rA[i])); x1 ^= x0; }
  x0 += ks1; x1 += ks2 + 1u;
#pragma unroll
  for (int i = 0; i < 4; ++i) { x0 += x1; x1 = (x1 << rB[i]) | (x1 >> (32 - rB[i])); x1 ^= x0; }
  x0 += ks2; x1 += ks0 + 2u;
#pragma unroll
  for (int i = 0; i < 4; ++i) { x0 += x1; x1 = (x1 << rA[i]) | (x1 >> (32 - rA[i])); x1 ^= x0; }
  x0 += ks0; x1 += ks1 + 3u;
#pragma unroll
  for (int i = 0; i < 4; ++i) { x0 += x1; x1 = (x1 << rB[i]) | (x1 >> (32 - rB[i])); x1 ^= x0; }
  x0 += ks1; x1 += ks2 + 4u;
#pragma unroll
  for (int i = 0; i < 4; ++i) { x0 += x1; x1 = (x1 << rA[i]) | (x1 >> (32 - rA[i])); x1 ^= x0; }
  o0 = x0 + ks2; o1 = x1 + ks0 + 5u;
}

__device__ __forceinline__ float gumbel_from_bits(uint32_t bits) {
  uint32_t fb = (bits >> 9) | 0x3f800000u;
  float u = __uint_as_float(fb) - 1.0f;
  u = fmaxf(u, 1.17549435e-38f);
  return -logf(-logf(u));
}

__device__ __forceinline__ float sigm(float x) { return 1.0f / (1.0f + __expf(-x)); }
__device__ __forceinline__ float tanh_(float x) {
  float e = __expf(2.0f * x);
  return 1.0f - 2.0f / (e + 1.0f);
}

__device__ __forceinline__ float dot64(const float* __restrict__ w, const float* h) {
  float a = 0.f;
#pragma unroll
  for (int k = 0; k < 64; ++k) a = fmaf(w[k], h[k], a);
  return a;
}

// Team-of-4 categorical sample + logprob. Lane g owns candidates c = g + 4*i.
template <int N>
__device__ __forceinline__ void samp_team(const float* lg, int g, int C,
                                          uint32_t k0, uint32_t k1, int b,
                                          int& sOut, float& lpOut) {
  float m = -__builtin_inff();
#pragma unroll
  for (int i = 0; i < N; ++i) m = fmaxf(m, lg[i]);
  m = fmaxf(m, __shfl_xor(m, 1));
  m = fmaxf(m, __shfl_xor(m, 2));
  float se = 0.f;
#pragma unroll
  for (int i = 0; i < N; ++i) se += expf(lg[i] - m);
  se += __shfl_xor(se, 1);
  se += __shfl_xor(se, 2);
  const float lse = logf(se);
  float bz = -__builtin_inff(), bl = 0.f;
  int bi = 0x7fffffff;
#pragma unroll
  for (int i = 0; i < N; ++i) {
    const int c = g + 4 * i;
    uint32_t o0, o1; tf2x32(k0, k1, 0u, (uint32_t)(b * C + c), o0, o1);
    const float z = lg[i] + gumbel_from_bits(o0 ^ o1);
    if (z > bz || (z == bz && c < bi)) { bz = z; bi = c; bl = lg[i]; }
  }
#pragma unroll
  for (int d = 1; d <= 2; d <<= 1) {
    const float z2 = __shfl_xor(bz, d);
    const int i2 = __shfl_xor(bi, d);
    const float l2 = __shfl_xor(bl, d);
    if (z2 > bz || (z2 == bz && i2 < bi)) { bz = z2; bi = i2; bl = l2; }
  }
  sOut = bi;
  lpOut = (bl - m) - lse;
}

// ---------------- kernel A: packed precompute ----------------
// Gate-interleaved index j' = unit*4 + gate  (gate order i,f,g,o; j = gate*64+unit)
// embedWi[v][j'] = b_ih[j] + b_hh[j] + sum_k embed[v][k]*W_ih[j][k]
// Wp[k*320 + G*20 + t] = W_hh[j][k], j' = 16G + t (t<16; t>=16 pad)
//   (+4-float group padding -> per-wave weight reads land on banks {0,4,..,28}:
//    conflict-free ds_read_b128)
__global__ __launch_bounds__(256) void k_prep(
    const float* __restrict__ embed, const float* __restrict__ W_ih,
    const float* __restrict__ W_hh, const float* __restrict__ b_ih,
    const float* __restrict__ b_hh, float* __restrict__ embedWi,
    float* __restrict__ Wp) {
  if (blockIdx.x >= NV) {
    int idx = (blockIdx.x - NV) * 256 + threadIdx.x;  // 0..20479
    int k = idx / 320, r = idx % 320;
    int G = r / 20, t = r % 20;
    float val = 0.f;
    if (t < 16) {
      int jp = G * 16 + t;
      int j = (jp & 3) * 64 + (jp >> 2);
      val = W_hh[j * 64 + k];
    }
    Wp[idx] = val;
    return;
  }
  __shared__ float er[64];
  int v = blockIdx.x;
  if (threadIdx.x < 64) er[threadIdx.x] = embed[v * 64 + threadIdx.x];
  __syncthreads();
  int jp = threadIdx.x;
  int j = (jp & 3) * 64 + (jp >> 2);
  float a = b_ih[j] + b_hh[j];
#pragma unroll
  for (int k = 0; k < 64; ++k) a = fmaf(W_ih[j * 64 + k], er[k], a);
  embedWi[v * 256 + jp] = a;
}

// ---------------- kernel B: LSTM, 8x16 lane-tile ----------------
// 256 WGs x 256 thr (1 WG/CU, 4 waves, 1 wave/SIMD). WG = 128 rows x 64 units.
// Wave: row-half (wave&1), unit-half (wave>>1). Lane: rg=lane&7 -> 8 rows,
// jg=lane>>3 -> 4 units x 4 gates = 16 contiguous j' (gate-interleaved), so
// each lane owns 32 COMPLETE cells: activation + c stay in-register, no gate
// LDS round-trip, 1 barrier/step.
// Per k per wave: 2 b128 h (2-way bank, free) + 4 b128 W (conflict-free by
// padding) = 72 LDS cyc vs 128 FMA = 256 VALU cyc. Per CU: LDS 288 vs VALU
// 256 cyc/k -> ~1.13x over the 218us chip FMA floor (r4's broadcast was 3x).
__global__ __launch_bounds__(256, 1) void k_lstm(
    const int* __restrict__ inst0, const int* __restrict__ inst1,
    const float* __restrict__ embedWi, const float* __restrict__ Wp,
    float* __restrict__ hT) {
  extern __shared__ float sm[];
  float* Wlds = sm;                       // 64*320 = 20480 floats (80 KB)
  float* hb = sm + 20480;                 // 2 x [64 k][128 row] (64 KB)
  int* idsb = (int*)(sm + 20480 + 16384); // 2 x 128 ids

  const int tid = threadIdx.x;
  const int lane = tid & 63;
  const int wave = tid >> 6;            // 0..3
  const int rg = lane & 7;
  const int jg = lane >> 3;
  const int wr = (wave & 1) * 64;       // row half
  const int G = jg + (wave >> 1) * 8;   // j'-group 0..15 (units 4G..4G+4)
  const int rloc = wr + rg * 8;         // wave-local row base (0..120)
  const int blk = blockIdx.x;
  const int rowbase = (blk & 127) * 128;
  const int* __restrict__ inst = (blk >> 7) ? inst1 : inst0;

  // stage packed weights; zero h buffer 0
  for (int i = tid; i < 5120; i += 256)
    ((float4*)Wlds)[i] = ((const float4*)Wp)[i];
  for (int i = tid; i < 8192; i += 256) hb[i] = 0.f;
  if (tid < 128) idsb[tid] = inst[(rowbase + tid) * NSEQ];

  float c[4][8];
#pragma unroll
  for (int du = 0; du < 4; ++du)
#pragma unroll
    for (int i = 0; i < 8; ++i) c[du][i] = 0.f;

  __syncthreads();

  int cur = 0;
#pragma unroll 1
  for (int t = 0; t < NSEQ; ++t) {
    // vocab ids for my 8 rows (LDS, staged)
    int4 va = *(const int4*)(idsb + (t & 1) * 128 + rloc);
    int4 vb = *(const int4*)(idsb + (t & 1) * 128 + rloc + 4);
    const int vv[8] = {va.x, va.y, va.z, va.w, vb.x, vb.y, vb.z, vb.w};
    // embedW rows: issue now, consume in epilogue (held in regs; 1 wave/SIMD
    // -> 512-VGPR budget, no pressure)
    float4 es[8][4];
#pragma unroll
    for (int i = 0; i < 8; ++i) {
      const float4* ep = (const float4*)(embedWi + vv[i] * 256 + G * 16);
      es[i][0] = ep[0]; es[i][1] = ep[1]; es[i][2] = ep[2]; es[i][3] = ep[3];
    }
    // prefetch next step's ids
    if (tid < 128 && t + 1 < NSEQ)
      idsb[((t + 1) & 1) * 128 + tid] = inst[(rowbase + tid) * NSEQ + t + 1];

    float acc[16][8];
#pragma unroll
    for (int q = 0; q < 16; ++q)
#pragma unroll
      for (int i = 0; i < 8; ++i) acc[q][i] = 0.f;

    const float* __restrict__ hcur = hb + cur * 8192;
    const float* __restrict__ wbase = Wlds + G * 20;
#pragma unroll 2
    for (int k = 0; k < 64; ++k) {
      const float4 h0 = *(const float4*)(hcur + k * 128 + rloc);
      const float4 h1 = *(const float4*)(hcur + k * 128 + rloc + 4);
      const float4* wk = (const float4*)(wbase + k * 320);
      const float4 w0 = wk[0], w1 = wk[1], w2 = wk[2], w3 = wk[3];
      const float h[8] = {h0.x, h0.y, h0.z, h0.w, h1.x, h1.y, h1.z, h1.w};
#pragma unroll
      for (int i = 0; i < 8; ++i) {
        acc[0][i]  = fmaf(w0.x, h[i], acc[0][i]);
        acc[1][i]  = fmaf(w0.y, h[i], acc[1][i]);
        acc[2][i]  = fmaf(w0.z, h[i], acc[2][i]);
        acc[3][i]  = fmaf(w0.w, h[i], acc[3][i]);
        acc[4][i]  = fmaf(w1.x, h[i], acc[4][i]);
        acc[5][i]  = fmaf(w1.y, h[i], acc[5][i]);
        acc[6][i]  = fmaf(w1.z, h[i], acc[6][i]);
        acc[7][i]  = fmaf(w1.w, h[i], acc[7][i]);
        acc[8][i]  = fmaf(w2.x, h[i], acc[8][i]);
        acc[9][i]  = fmaf(w2.y, h[i], acc[9][i]);
        acc[10][i] = fmaf(w2.z, h[i], acc[10][i]);
        acc[11][i] = fmaf(w2.w, h[i], acc[11][i]);
        acc[12][i] = fmaf(w3.x, h[i], acc[12][i]);
        acc[13][i] = fmaf(w3.y, h[i], acc[13][i]);
        acc[14][i] = fmaf(w3.z, h[i], acc[14][i]);
        acc[15][i] = fmaf(w3.w, h[i], acc[15][i]);
      }
    }

    // epilogue: 32 complete cells in-register (j' quad q = gates i,f,g,o of
    // unit 4G+q), matching es[i][q] gate quad exactly
    float* __restrict__ hnxt = hb + (cur ^ 1) * 8192;
#pragma unroll
    for (int du = 0; du < 4; ++du) {
      const int u = 4 * G + du;
      float hv[8];
#pragma unroll
      for (int i = 0; i < 8; ++i) {
        const float iv = acc[du * 4 + 0][i] + es[i][du].x;
        const float fv = acc[du * 4 + 1][i] + es[i][du].y;
        const float gv = acc[du * 4 + 2][i] + es[i][du].z;
        const float ov = acc[du * 4 + 3][i] + es[i][du].w;
        const float ci = sigm(fv) * c[du][i] + sigm(iv) * tanh_(gv);
        c[du][i] = ci;
        hv[i] = sigm(ov) * tanh_(ci);
      }
      *(float4*)(hnxt + u * 128 + rloc)     = (float4){hv[0], hv[1], hv[2], hv[3]};
      *(float4*)(hnxt + u * 128 + rloc + 4) = (float4){hv[4], hv[5], hv[6], hv[7]};
    }
    __syncthreads();
    cur ^= 1;
  }

  // final store: hT[u][flat], coalesced
  const float* __restrict__ hf = hb + cur * 8192;
  for (int idx = tid; idx < 8192; idx += 256) {
    const int u = idx >> 7, r = idx & 127;
    hT[u * NROWS + blk * 128 + r] = hf[idx];
  }
}

// ---------------- kernel C: heads, 4-lane team per row (bit-exact r5) ------
__global__ __launch_bounds__(256) void k_heads(
    const int* __restrict__ canvas0, const int* __restrict__ canvas1,
    const int* __restrict__ ref,
    const float* __restrict__ Wc, const float* __restrict__ bc,
    const float* __restrict__ Ws, const float* __restrict__ bs,
    const float* __restrict__ Wl, const float* __restrict__ bl,
    const float* __restrict__ Wr1, const float* __restrict__ br1,
    const float* __restrict__ Wr2, const float* __restrict__ br2,
    const float* __restrict__ Wp, const float* __restrict__ bp,
    const float* __restrict__ hT, float* __restrict__ out) {
  const int tid = threadIdx.x;
  const int g = tid & 3;
  const int s = blockIdx.x & 1;
  const int b = (blockIdx.x >> 1) * 64 + (tid >> 2);
  const float NEG = -__builtin_inff();

  uint32_t kk0[7], kk1[7];
#pragma unroll
  for (int i = 0; i < 7; ++i) {
    uint32_t o0, o1; tf2x32(0u, 42u, 0u, (uint32_t)i, o0, o1);
    kk0[i] = o0; kk1[i] = o1;
  }

  float h[64];
#pragma unroll
  for (int u = 0; u < 64; ++u) h[u] = hT[u * NROWS + s * NB + b];

  float lgc[1], lgs[1];
  lgc[0] = (g < 3) ? (bc[g] + dot64(Wc + g * 64, h)) : NEG;
  lgs[0] = (g < 3) ? (bs[g] + dot64(Ws + g * 64, h)) : NEG;

  if (s == 0) {
    int cs0, ss0, loc0; float clp0, slp0, llp0;
    samp_team<1>(lgc, g, 3, kk0[0], kk1[0], b, cs0, clp0);
    samp_team<1>(lgs, g, 3, kk0[1], kk1[1], b, ss0, slp0);
    float lgl[7];
#pragma unroll
    for (int i = 0; i < 7; ++i) {
      const int cc = g + 4 * i;
      lgl[i] = (cc < 25) ? (bl[cc] + dot64(Wl + cc * 64, h)) : NEG;
    }
    samp_team<7>(lgl, g, 25, kk0[2], kk1[2], b, loc0, llp0);

    if (g == 0) {
      const int p0 = min(max(loc0, 0), 24);
      const int4 pt = ((const int4*)(canvas1 + b * 100))[p0];
      const bool ok0 = (loc0 >= 0) && (loc0 < 25) && (pt.x + pt.y + pt.z + pt.w >= 0);
      const float loc_r0 = ok0 ? 1.f : -1.f;
      const float col_r0 = ok0 ? ((cs0 == pt.x) ? 1.f : -1.f) : 0.f;
      out[0 * NB + b] = clp0;
      out[1 * NB + b] = slp0;
      out[2 * NB + b] = llp0;
      out[7 * NB + b] = loc_r0;
      out[8 * NB + b] = col_r0;
      out[9 * NB + b] = loc_r0;
    }
  } else {
    int cs1, ss1, ls1; float clp1, slp1, llp1;
    samp_team<1>(lgc, g, 3, kk0[3], kk1[3], b, cs1, clp1);
    samp_team<1>(lgs, g, 3, kk0[4], kk1[4], b, ss1, slp1);
    float lgp[2];
#pragma unroll
    for (int i = 0; i < 2; ++i) {
      const int cc = g + 4 * i;
      lgp[i] = bp[cc] + dot64(Wp + cc * 64, h);
    }
    samp_team<2>(lgp, g, 8, kk0[5], kk1[5], b, ls1, llp1);

    float uv8[8], w64[8], w65[8], w66[8], w67[8], wr2[8];
#pragma unroll
    for (int i = 0; i < 8; ++i) {
      const int j = g + 4 * i;
      uv8[i] = br1[j] + dot64(Wr1 + j * 68, h);
      const float* wr = Wr1 + j * 68 + 64;
      w64[i] = wr[0]; w65[i] = wr[1]; w66[i] = wr[2]; w67[i] = wr[3];
      wr2[i] = Wr2[j];
    }
    float lgA[7];
#pragma unroll
    for (int i = 0; i < 7; ++i) lgA[i] = NEG;
    const float b2 = br2[0];
#pragma unroll
    for (int p = 0; p < 25; ++p) {
      const int4 c4 = ((const int4*)(canvas0 + b * 100))[p];
      const float f0 = (float)c4.x, f1 = (float)c4.y;
      const float f2 = (float)c4.z, f3 = (float)c4.w;
      float part = 0.f;
#pragma unroll
      for (int i = 0; i < 8; ++i) {
        float hj = uv8[i];
        hj = fmaf(w64[i], f0, hj);
        hj = fmaf(w65[i], f1, hj);
        hj = fmaf(w66[i], f2, hj);
        hj = fmaf(w67[i], f3, hj);
        part = fmaf(wr2[i], fmaxf(hj, 0.f), part);
      }
      part += __shfl_xor(part, 1);
      part += __shfl_xor(part, 2);
      const float ap = b2 + part;
      if ((p & 3) == g) lgA[p >> 2] = ap;
    }
    int att_s; float alp1;
    samp_team<7>(lgA, g, 25, kk0[6], kk1[6], b, att_s, alp1);

    if (g == 0) {
      const int4 r4 = ((const int4*)(canvas0 + b * 100))[att_s];
      const int4 rr = *(const int4*)(ref + b * 4);
      const bool match = (r4.x == rr.x) && (r4.y == rr.y) &&
                         (r4.z == rr.z) && (r4.w == rr.w);
      const float att_reward = match ? 1.f : -1.f;
      const int ox = (int)((0x22001120u >> (ls1 * 4)) & 0xFu) - 1;
      const int oy = (int)((0x20200211u >> (ls1 * 4)) & 0xFu) - 1;
      const int loc1 = (r4.z + ox) * 5 + (r4.w + oy);
      const int p1 = min(max(loc1, 0), 24);
      const int4 q4 = ((const int4*)(canvas1 + b * 100))[p1];
      const bool ok1 = (loc1 >= 0) && (loc1 < 25) && (q4.x + q4.y + q4.z + q4.w >= 0);
      const float loc_r1 = ok1 ? 1.f : -1.f;
      const float col_r1 = ok1 ? ((cs1 == q4.x) ? 1.f : -1.f) : 0.f;
      out[3 * NB + b]  = clp1;
      out[4 * NB + b]  = slp1;
      out[5 * NB + b]  = llp1;
      out[6 * NB + b]  = alp1;
      out[10 * NB + b] = loc_r1;
      out[11 * NB + b] = col_r1;
      out[12 * NB + b] = loc_r1;
      out[13 * NB + b] = att_reward;
    }
  }
}

extern "C" void kernel_launch(void* const* d_in, const int* in_sizes, int n_in,
                              void* d_out, int out_size, void* d_ws, size_t ws_size,
                              hipStream_t stream) {
  const int* inst0 = (const int*)d_in[0];
  const int* inst1 = (const int*)d_in[1];
  const int* canvas0 = (const int*)d_in[2];
  const int* canvas1 = (const int*)d_in[3];
  const int* ref = (const int*)d_in[4];
  const float* embed = (const float*)d_in[5];
  const float* W_ih = (const float*)d_in[6];
  const float* W_hh = (const float*)d_in[7];
  const float* b_ih = (const float*)d_in[8];
  const float* b_hh = (const float*)d_in[9];
  const float* Wc = (const float*)d_in[10];
  const float* bc = (const float*)d_in[11];
  const float* Ws = (const float*)d_in[12];
  const float* bs = (const float*)d_in[13];
  const float* Wl = (const float*)d_in[14];
  const float* bl = (const float*)d_in[15];
  const float* Wr1 = (const float*)d_in[16];
  const float* br1 = (const float*)d_in[17];
  const float* Wr2 = (const float*)d_in[18];
  const float* br2 = (const float*)d_in[19];
  const float* Wp = (const float*)d_in[20];
  const float* bp = (const float*)d_in[21];

  float* ws = (float*)d_ws;
  float* embedWi = ws;                      // 1001*256
  float* Wpk = embedWi + NV * 256;          // 64*320 packed padded
  float* hT = Wpk + 64 * 320;               // 64*32768
  float* out = (float*)d_out;

  // opt in to >64KB dynamic LDS (idempotent, capture-safe)
  (void)hipFuncSetAttribute((const void*)k_lstm,
                            hipFuncAttributeMaxDynamicSharedMemorySize, 163840);

  const size_t ldsBytes = (20480 + 16384 + 64) * 4;  // W + h dbuf + ids
  k_prep<<<NV + 80, 256, 0, stream>>>(embed, W_ih, W_hh, b_ih, b_hh, embedWi, Wpk);
  k_lstm<<<256, 256, ldsBytes, stream>>>(inst0, inst1, embedWi, Wpk, hT);
  k_heads<<<512, 256, 0, stream>>>(canvas0, canvas1, ref, Wc, bc, Ws, bs,
                                   Wl, bl, Wr1, br1, Wr2, br2, Wp, bp, hT, out);
}

// Round 7
// 716.068 us; speedup vs baseline: 1.2320x; 1.1533x over previous
//
#include <hip/hip_runtime.h>
#include <stdint.h>
#include <math.h>

#define NB 16384      // batch
#define NSEQ 32       // sequence length
#define NV 1001       // vocab (V+1)
#define NROWS 32768   // 2 * NB flattened rows

// ---------------- threefry2x32 (JAX-exact) ----------------
__device__ __forceinline__ void tf2x32(uint32_t k0, uint32_t k1,
                                       uint32_t x0, uint32_t x1,
                                       uint32_t& o0, uint32_t& o1) {
  const uint32_t ks0 = k0, ks1 = k1, ks2 = k0 ^ k1 ^ 0x1BD11BDAu;
  x0 += ks0; x1 += ks1;
  const int rA[4] = {13, 15, 26, 6};
  const int rB[4] = {17, 29, 16, 24};
#pragma unroll
  for (int i = 0; i < 4; ++i) { x0 += x1; x1 = (x1 << rA[i]) | (x1 >> (32 - rA[i])); x1 ^= x0; }
  x0 += ks1; x1 += ks2 + 1u;
#pragma unroll
  for (int i = 0; i < 4; ++i) { x0 += x1; x1 = (x1 << rB[i]) | (x1 >> (32 - rB[i])); x1 ^= x0; }
  x0 += ks2; x1 += ks0 + 2u;
#pragma unroll
  for (int i = 0; i < 4; ++i) { x0 += x1; x1 = (x1 << rA[i]) | (x1 >> (32 - rA[i])); x1 ^= x0; }
  x0 += ks0; x1 += ks1 + 3u;
#pragma unroll
  for (int i = 0; i < 4; ++i) { x0 += x1; x1 = (x1 << rB[i]) | (x1 >> (32 - rB[i])); x1 ^= x0; }
  x0 += ks1; x1 += ks2 + 4u;
#pragma unroll
  for (int i = 0; i < 4; ++i) { x0 += x1; x1 = (x1 << rA[i]) | (x1 >> (32 - rA[i])); x1 ^= x0; }
  o0 = x0 + ks2; o1 = x1 + ks0 + 5u;
}

__device__ __forceinline__ float gumbel_from_bits(uint32_t bits) {
  uint32_t fb = (bits >> 9) | 0x3f800000u;
  float u = __uint_as_float(fb) - 1.0f;
  u = fmaxf(u, 1.17549435e-38f);
  return -logf(-logf(u));
}

__device__ __forceinline__ float sigm(float x) { return 1.0f / (1.0f + __expf(-x)); }
__device__ __forceinline__ float tanh_(float x) {
  float e = __expf(2.0f * x);
  return 1.0f - 2.0f / (e + 1.0f);
}

__device__ __forceinline__ float dot64(const float* __restrict__ w, const float* h) {
  float a = 0.f;
#pragma unroll
  for (int k = 0; k < 64; ++k) a = fmaf(w[k], h[k], a);
  return a;
}

// Team-of-4 categorical sample + logprob. Lane g owns candidates c = g + 4*i.
template <int N>
__device__ __forceinline__ void samp_team(const float* lg, int g, int C,
                                          uint32_t k0, uint32_t k1, int b,
                                          int& sOut, float& lpOut) {
  float m = -__builtin_inff();
#pragma unroll
  for (int i = 0; i < N; ++i) m = fmaxf(m, lg[i]);
  m = fmaxf(m, __shfl_xor(m, 1));
  m = fmaxf(m, __shfl_xor(m, 2));
  float se = 0.f;
#pragma unroll
  for (int i = 0; i < N; ++i) se += expf(lg[i] - m);
  se += __shfl_xor(se, 1);
  se += __shfl_xor(se, 2);
  const float lse = logf(se);
  float bz = -__builtin_inff(), bl = 0.f;
  int bi = 0x7fffffff;
#pragma unroll
  for (int i = 0; i < N; ++i) {
    const int c = g + 4 * i;
    uint32_t o0, o1; tf2x32(k0, k1, 0u, (uint32_t)(b * C + c), o0, o1);
    const float z = lg[i] + gumbel_from_bits(o0 ^ o1);
    if (z > bz || (z == bz && c < bi)) { bz = z; bi = c; bl = lg[i]; }
  }
#pragma unroll
  for (int d = 1; d <= 2; d <<= 1) {
    const float z2 = __shfl_xor(bz, d);
    const int i2 = __shfl_xor(bi, d);
    const float l2 = __shfl_xor(bl, d);
    if (z2 > bz || (z2 == bz && i2 < bi)) { bz = z2; bi = i2; bl = l2; }
  }
  sOut = bi;
  lpOut = (bl - m) - lse;
}

// ---------------- kernel A: packed precompute ----------------
// Gate-interleaved j' = unit*4 + gate (gate order i,f,g,o; torch j = gate*64+unit)
// embedWi[v][j'] = b_ih[j] + b_hh[j] + sum_k embed[v][k]*W_ih[j][k]
// Wp[k*384 + G*12 + t] = W_hh[j][k], j' = 8G + t (t<8; t in 8..11 = pad 0)
//   pad-12 groups: wave reads (12*jg mod 32) start banks all distinct ->
//   1-phase (perfectly spread) ds_read_b128.
__global__ __launch_bounds__(256) void k_prep(
    const float* __restrict__ embed, const float* __restrict__ W_ih,
    const float* __restrict__ W_hh, const float* __restrict__ b_ih,
    const float* __restrict__ b_hh, float* __restrict__ embedWi,
    float* __restrict__ Wp) {
  if (blockIdx.x >= NV) {
    int idx = (blockIdx.x - NV) * 256 + threadIdx.x;  // 0..24575
    int k = idx / 384, r = idx % 384;
    int G = r / 12, t = r % 12;
    float val = 0.f;
    if (t < 8) {
      int jp = G * 8 + t;
      int j = (jp & 3) * 64 + (jp >> 2);
      val = W_hh[j * 64 + k];
    }
    Wp[idx] = val;
    return;
  }
  __shared__ float er[64];
  int v = blockIdx.x;
  if (threadIdx.x < 64) er[threadIdx.x] = embed[v * 64 + threadIdx.x];
  __syncthreads();
  int jp = threadIdx.x;
  int j = (jp & 3) * 64 + (jp >> 2);
  float a = b_ih[j] + b_hh[j];
#pragma unroll
  for (int k = 0; k < 64; ++k) a = fmaf(W_ih[j * 64 + k], er[k], a);
  embedWi[v * 256 + jp] = a;
}

// ---------------- kernel B: LSTM, 8x8 lane-tile, 8 waves (2/SIMD) ----------
// 256 WGs x 512 thr, 1 WG/CU. WG = 128 rows x 256 j'. Wave = 64 rows x 64 j'
// (wr2 = wave&1 row-half, jq = wave>>1 j'-quarter). Lane = 8 rows x 8 j'
// (rg=lane&7, jg=lane>>3): 8 j' = 2 COMPLETE cells (gate-interleaved) -> no
// gate LDS round-trip, c in regs. acc 64 + es 64 regs fit the (512,2) 256-VGPR
// budget (r6's 8x16 tile forced es loads into the epilogue = exposed latency).
// Per wave per k: 2 b128 W (bank-perfect) + 2 b128 h (2-way, free) vs 64 FMA.
// h single-buffered (32 KB), 2 barriers/step; LDS total 129 KB.
__global__ __launch_bounds__(512, 2) void k_lstm(
    const int* __restrict__ inst0, const int* __restrict__ inst1,
    const float* __restrict__ embedWi, const float* __restrict__ Wp,
    float* __restrict__ hT) {
  extern __shared__ float sm[];
  float* Wlds = sm;                      // [64 k][384] 96 KB
  float* hb = sm + 24576;                // [64 unit][128 row] 32 KB
  int* idsb = (int*)(sm + 24576 + 8192); // [2][128]

  const int tid = threadIdx.x;
  const int lane = tid & 63;
  const int wave = tid >> 6;        // 0..7
  const int wr2 = wave & 1;
  const int jq = wave >> 1;
  const int rg = lane & 7;
  const int jg = lane >> 3;
  const int rloc = wr2 * 64 + rg * 8;   // block-local row base (8 rows)
  const int G = jq * 8 + jg;            // j'-group of 8 (0..31)
  const int jpb = G * 8;                // j' base; units 2G, 2G+1
  const int blk = blockIdx.x;
  const int rowbase = blk * 128;        // flat rows
  const int rb = rowbase & (NB - 1);
  const int* __restrict__ inst = (blk < 128) ? inst0 : inst1;

  for (int i = tid; i < 6144; i += 512)
    ((float4*)Wlds)[i] = ((const float4*)Wp)[i];
  for (int i = tid; i < 8192; i += 512) hb[i] = 0.f;
  if (tid < 128) idsb[tid] = inst[(rb + tid) * NSEQ];

  float c[2][8];
#pragma unroll
  for (int d = 0; d < 2; ++d)
#pragma unroll
    for (int i = 0; i < 8; ++i) c[d][i] = 0.f;

  __syncthreads();

#pragma unroll 1
  for (int t = 0; t < NSEQ; ++t) {
    // ids of my 8 rows; es = embedW gate-quads for my 2 units x 8 rows,
    // issued now, consumed in epilogue (held in regs; ~24k cyc to land)
    const int* ip = idsb + (t & 1) * 128 + rloc;
    const int4 ia = *(const int4*)(ip);
    const int4 ib = *(const int4*)(ip + 4);
    const int vv[8] = {ia.x, ia.y, ia.z, ia.w, ib.x, ib.y, ib.z, ib.w};
    float4 es[8][2];
#pragma unroll
    for (int i = 0; i < 8; ++i) {
      const float4* ep = (const float4*)(embedWi + vv[i] * 256 + jpb);
      es[i][0] = ep[0];
      es[i][1] = ep[1];
    }
    if (tid < 128 && t + 1 < NSEQ)
      idsb[((t + 1) & 1) * 128 + tid] = inst[(rb + tid) * NSEQ + t + 1];

    float acc[8][8];  // [j_local][row]
#pragma unroll
    for (int j = 0; j < 8; ++j)
#pragma unroll
      for (int i = 0; i < 8; ++i) acc[j][i] = 0.f;

    const float* __restrict__ wb0 = Wlds + G * 12;
#pragma unroll 1
    for (int kh = 0; kh < 2; ++kh) {   // split keeps ds offsets < 64 KB
      const float* __restrict__ hp = hb + kh * 4096;
      const float* __restrict__ wp2 = wb0 + kh * 12288;
#pragma unroll 4
      for (int k = 0; k < 32; ++k) {
        const float4 w0 = *(const float4*)(wp2 + k * 384);
        const float4 w1 = *(const float4*)(wp2 + k * 384 + 4);
        const float4 h0 = *(const float4*)(hp + k * 128 + rloc);
        const float4 h1 = *(const float4*)(hp + k * 128 + rloc + 4);
        const float wv[8] = {w0.x, w0.y, w0.z, w0.w, w1.x, w1.y, w1.z, w1.w};
        const float hv[8] = {h0.x, h0.y, h0.z, h0.w, h1.x, h1.y, h1.z, h1.w};
#pragma unroll
        for (int j = 0; j < 8; ++j)
#pragma unroll
          for (int i = 0; i < 8; ++i)
            acc[j][i] = fmaf(wv[j], hv[i], acc[j][i]);
      }
    }
    __syncthreads();  // all h_t reads complete

    // epilogue: 16 complete cells (2 units x 8 rows), in-register
#pragma unroll
    for (int d = 0; d < 2; ++d) {
      const int u = 2 * G + d;
      float hv[8];
#pragma unroll
      for (int i = 0; i < 8; ++i) {
        const float iv = acc[d * 4 + 0][i] + es[i][d].x;
        const float fv = acc[d * 4 + 1][i] + es[i][d].y;
        const float gv = acc[d * 4 + 2][i] + es[i][d].z;
        const float ov = acc[d * 4 + 3][i] + es[i][d].w;
        const float ci = sigm(fv) * c[d][i] + sigm(iv) * tanh_(gv);
        c[d][i] = ci;
        hv[i] = sigm(ov) * tanh_(ci);
      }
      *(float4*)(hb + u * 128 + rloc) = (float4){hv[0], hv[1], hv[2], hv[3]};
      *(float4*)(hb + u * 128 + rloc + 4) = (float4){hv[4], hv[5], hv[6], hv[7]};
    }
    __syncthreads();  // h_{t+1} visible
  }

  // final store: hT[u][flat], coalesced
  for (int idx = tid; idx < 8192; idx += 512) {
    const int u = idx >> 7, r = idx & 127;
    hT[u * NROWS + rowbase + r] = hb[idx];
  }
}

// ---------------- kernel C: heads, 4-lane team per row (bit-exact r5/r6) ---
__global__ __launch_bounds__(256) void k_heads(
    const int* __restrict__ canvas0, const int* __restrict__ canvas1,
    const int* __restrict__ ref,
    const float* __restrict__ Wc, const float* __restrict__ bc,
    const float* __restrict__ Ws, const float* __restrict__ bs,
    const float* __restrict__ Wl, const float* __restrict__ bl,
    const float* __restrict__ Wr1, const float* __restrict__ br1,
    const float* __restrict__ Wr2, const float* __restrict__ br2,
    const float* __restrict__ Wp, const float* __restrict__ bp,
    const float* __restrict__ hT, float* __restrict__ out) {
  const int tid = threadIdx.x;
  const int g = tid & 3;
  const int s = blockIdx.x & 1;
  const int b = (blockIdx.x >> 1) * 64 + (tid >> 2);
  const float NEG = -__builtin_inff();

  uint32_t kk0[7], kk1[7];
#pragma unroll
  for (int i = 0; i < 7; ++i) {
    uint32_t o0, o1; tf2x32(0u, 42u, 0u, (uint32_t)i, o0, o1);
    kk0[i] = o0; kk1[i] = o1;
  }

  float h[64];
#pragma unroll
  for (int u = 0; u < 64; ++u) h[u] = hT[u * NROWS + s * NB + b];

  float lgc[1], lgs[1];
  lgc[0] = (g < 3) ? (bc[g] + dot64(Wc + g * 64, h)) : NEG;
  lgs[0] = (g < 3) ? (bs[g] + dot64(Ws + g * 64, h)) : NEG;

  if (s == 0) {
    int cs0, ss0, loc0; float clp0, slp0, llp0;
    samp_team<1>(lgc, g, 3, kk0[0], kk1[0], b, cs0, clp0);
    samp_team<1>(lgs, g, 3, kk0[1], kk1[1], b, ss0, slp0);
    float lgl[7];
#pragma unroll
    for (int i = 0; i < 7; ++i) {
      const int cc = g + 4 * i;
      lgl[i] = (cc < 25) ? (bl[cc] + dot64(Wl + cc * 64, h)) : NEG;
    }
    samp_team<7>(lgl, g, 25, kk0[2], kk1[2], b, loc0, llp0);

    if (g == 0) {
      const int p0 = min(max(loc0, 0), 24);
      const int4 pt = ((const int4*)(canvas1 + b * 100))[p0];
      const bool ok0 = (loc0 >= 0) && (loc0 < 25) && (pt.x + pt.y + pt.z + pt.w >= 0);
      const float loc_r0 = ok0 ? 1.f : -1.f;
      const float col_r0 = ok0 ? ((cs0 == pt.x) ? 1.f : -1.f) : 0.f;
      out[0 * NB + b] = clp0;
      out[1 * NB + b] = slp0;
      out[2 * NB + b] = llp0;
      out[7 * NB + b] = loc_r0;
      out[8 * NB + b] = col_r0;
      out[9 * NB + b] = loc_r0;
    }
  } else {
    int cs1, ss1, ls1; float clp1, slp1, llp1;
    samp_team<1>(lgc, g, 3, kk0[3], kk1[3], b, cs1, clp1);
    samp_team<1>(lgs, g, 3, kk0[4], kk1[4], b, ss1, slp1);
    float lgp[2];
#pragma unroll
    for (int i = 0; i < 2; ++i) {
      const int cc = g + 4 * i;
      lgp[i] = bp[cc] + dot64(Wp + cc * 64, h);
    }
    samp_team<2>(lgp, g, 8, kk0[5], kk1[5], b, ls1, llp1);

    float uv8[8], w64[8], w65[8], w66[8], w67[8], wr2[8];
#pragma unroll
    for (int i = 0; i < 8; ++i) {
      const int j = g + 4 * i;
      uv8[i] = br1[j] + dot64(Wr1 + j * 68, h);
      const float* wr = Wr1 + j * 68 + 64;
      w64[i] = wr[0]; w65[i] = wr[1]; w66[i] = wr[2]; w67[i] = wr[3];
      wr2[i] = Wr2[j];
    }
    float lgA[7];
#pragma unroll
    for (int i = 0; i < 7; ++i) lgA[i] = NEG;
    const float b2 = br2[0];
#pragma unroll
    for (int p = 0; p < 25; ++p) {
      const int4 c4 = ((const int4*)(canvas0 + b * 100))[p];
      const float f0 = (float)c4.x, f1 = (float)c4.y;
      const float f2 = (float)c4.z, f3 = (float)c4.w;
      float part = 0.f;
#pragma unroll
      for (int i = 0; i < 8; ++i) {
        float hj = uv8[i];
        hj = fmaf(w64[i], f0, hj);
        hj = fmaf(w65[i], f1, hj);
        hj = fmaf(w66[i], f2, hj);
        hj = fmaf(w67[i], f3, hj);
        part = fmaf(wr2[i], fmaxf(hj, 0.f), part);
      }
      part += __shfl_xor(part, 1);
      part += __shfl_xor(part, 2);
      const float ap = b2 + part;
      if ((p & 3) == g) lgA[p >> 2] = ap;
    }
    int att_s; float alp1;
    samp_team<7>(lgA, g, 25, kk0[6], kk1[6], b, att_s, alp1);

    if (g == 0) {
      const int4 r4 = ((const int4*)(canvas0 + b * 100))[att_s];
      const int4 rr = *(const int4*)(ref + b * 4);
      const bool match = (r4.x == rr.x) && (r4.y == rr.y) &&
                         (r4.z == rr.z) && (r4.w == rr.w);
      const float att_reward = match ? 1.f : -1.f;
      const int ox = (int)((0x22001120u >> (ls1 * 4)) & 0xFu) - 1;
      const int oy = (int)((0x20200211u >> (ls1 * 4)) & 0xFu) - 1;
      const int loc1 = (r4.z + ox) * 5 + (r4.w + oy);
      const int p1 = min(max(loc1, 0), 24);
      const int4 q4 = ((const int4*)(canvas1 + b * 100))[p1];
      const bool ok1 = (loc1 >= 0) && (loc1 < 25) && (q4.x + q4.y + q4.z + q4.w >= 0);
      const float loc_r1 = ok1 ? 1.f : -1.f;
      const float col_r1 = ok1 ? ((cs1 == q4.x) ? 1.f : -1.f) : 0.f;
      out[3 * NB + b]  = clp1;
      out[4 * NB + b]  = slp1;
      out[5 * NB + b]  = llp1;
      out[6 * NB + b]  = alp1;
      out[10 * NB + b] = loc_r1;
      out[11 * NB + b] = col_r1;
      out[12 * NB + b] = loc_r1;
      out[13 * NB + b] = att_reward;
    }
  }
}

extern "C" void kernel_launch(void* const* d_in, const int* in_sizes, int n_in,
                              void* d_out, int out_size, void* d_ws, size_t ws_size,
                              hipStream_t stream) {
  const int* inst0 = (const int*)d_in[0];
  const int* inst1 = (const int*)d_in[1];
  const int* canvas0 = (const int*)d_in[2];
  const int* canvas1 = (const int*)d_in[3];
  const int* ref = (const int*)d_in[4];
  const float* embed = (const float*)d_in[5];
  const float* W_ih = (const float*)d_in[6];
  const float* W_hh = (const float*)d_in[7];
  const float* b_ih = (const float*)d_in[8];
  const float* b_hh = (const float*)d_in[9];
  const float* Wc = (const float*)d_in[10];
  const float* bc = (const float*)d_in[11];
  const float* Ws = (const float*)d_in[12];
  const float* bs = (const float*)d_in[13];
  const float* Wl = (const float*)d_in[14];
  const float* bl = (const float*)d_in[15];
  const float* Wr1 = (const float*)d_in[16];
  const float* br1 = (const float*)d_in[17];
  const float* Wr2 = (const float*)d_in[18];
  const float* br2 = (const float*)d_in[19];
  const float* Wp = (const float*)d_in[20];
  const float* bp = (const float*)d_in[21];

  float* ws = (float*)d_ws;
  float* embedWi = ws;                      // 1001*256
  float* Wpk = embedWi + NV * 256;          // 64*384 packed padded
  float* hT = Wpk + 64 * 384;               // 64*32768
  float* out = (float*)d_out;

  // opt in to >64KB dynamic LDS (idempotent, capture-safe)
  (void)hipFuncSetAttribute((const void*)k_lstm,
                            hipFuncAttributeMaxDynamicSharedMemorySize, 163840);

  const size_t ldsBytes = (24576 + 8192 + 256) * 4;  // W + h + ids = 129 KB
  k_prep<<<NV + 96, 256, 0, stream>>>(embed, W_ih, W_hh, b_ih, b_hh, embedWi, Wpk);
  k_lstm<<<256, 512, ldsBytes, stream>>>(inst0, inst1, embedWi, Wpk, hT);
  k_heads<<<512, 256, 0, stream>>>(canvas0, canvas1, ref, Wc, bc, Ws, bs,
                                   Wl, bl, Wr1, br1, Wr2, br2, Wp, bp, hT, out);
}

// Round 8
// 472.530 us; speedup vs baseline: 1.8669x; 1.5154x over previous
//
#include <hip/hip_runtime.h>
#include <hip/hip_bf16.h>
#include <stdint.h>
#include <math.h>

#define NB 16384      // batch
#define NSEQ 32       // sequence length
#define NV 1001       // vocab (V+1)
#define NROWS 32768   // 2 * NB flattened rows

typedef __attribute__((ext_vector_type(8))) short bf16x8;
typedef __attribute__((ext_vector_type(4))) float f32x4;

// ---------------- threefry2x32 (JAX-exact) ----------------
__device__ __forceinline__ void tf2x32(uint32_t k0, uint32_t k1,
                                       uint32_t x0, uint32_t x1,
                                       uint32_t& o0, uint32_t& o1) {
  const uint32_t ks0 = k0, ks1 = k1, ks2 = k0 ^ k1 ^ 0x1BD11BDAu;
  x0 += ks0; x1 += ks1;
  const int rA[4] = {13, 15, 26, 6};
  const int rB[4] = {17, 29, 16, 24};
#pragma unroll
  for (int i = 0; i < 4; ++i) { x0 += x1; x1 = (x1 << rA[i]) | (x1 >> (32 - rA[i])); x1 ^= x0; }
  x0 += ks1; x1 += ks2 + 1u;
#pragma unroll
  for (int i = 0; i < 4; ++i) { x0 += x1; x1 = (x1 << rB[i]) | (x1 >> (32 - rB[i])); x1 ^= x0; }
  x0 += ks2; x1 += ks0 + 2u;
#pragma unroll
  for (int i = 0; i < 4; ++i) { x0 += x1; x1 = (x1 << rA[i]) | (x1 >> (32 - rA[i])); x1 ^= x0; }
  x0 += ks0; x1 += ks1 + 3u;
#pragma unroll
  for (int i = 0; i < 4; ++i) { x0 += x1; x1 = (x1 << rB[i]) | (x1 >> (32 - rB[i])); x1 ^= x0; }
  x0 += ks1; x1 += ks2 + 4u;
#pragma unroll
  for (int i = 0; i < 4; ++i) { x0 += x1; x1 = (x1 << rA[i]) | (x1 >> (32 - rA[i])); x1 ^= x0; }
  o0 = x0 + ks2; o1 = x1 + ks0 + 5u;
}

__device__ __forceinline__ float gumbel_from_bits(uint32_t bits) {
  uint32_t fb = (bits >> 9) | 0x3f800000u;
  float u = __uint_as_float(fb) - 1.0f;
  u = fmaxf(u, 1.17549435e-38f);
  return -logf(-logf(u));
}

__device__ __forceinline__ float sigm(float x) { return 1.0f / (1.0f + __expf(-x)); }
__device__ __forceinline__ float tanh_(float x) {
  float e = __expf(2.0f * x);
  return 1.0f - 2.0f / (e + 1.0f);
}

__device__ __forceinline__ float dot64(const float* __restrict__ w, const float* h) {
  float a = 0.f;
#pragma unroll
  for (int k = 0; k < 64; ++k) a = fmaf(w[k], h[k], a);
  return a;
}

// round-to-bf16 (RNE): returns bits, outputs rounded-back float
__device__ __forceinline__ unsigned short bfbits(float x, float& xf) {
  __hip_bfloat16 hb = __float2bfloat16(x);
  xf = __bfloat162float(hb);
  unsigned short u;
  __builtin_memcpy(&u, &hb, 2);
  return u;
}

// Team-of-4 categorical sample + logprob (bit-exact since r3 — do not touch)
template <int N>
__device__ __forceinline__ void samp_team(const float* lg, int g, int C,
                                          uint32_t k0, uint32_t k1, int b,
                                          int& sOut, float& lpOut) {
  float m = -__builtin_inff();
#pragma unroll
  for (int i = 0; i < N; ++i) m = fmaxf(m, lg[i]);
  m = fmaxf(m, __shfl_xor(m, 1));
  m = fmaxf(m, __shfl_xor(m, 2));
  float se = 0.f;
#pragma unroll
  for (int i = 0; i < N; ++i) se += expf(lg[i] - m);
  se += __shfl_xor(se, 1);
  se += __shfl_xor(se, 2);
  const float lse = logf(se);
  float bz = -__builtin_inff(), bl = 0.f;
  int bi = 0x7fffffff;
#pragma unroll
  for (int i = 0; i < N; ++i) {
    const int c = g + 4 * i;
    uint32_t o0, o1; tf2x32(k0, k1, 0u, (uint32_t)(b * C + c), o0, o1);
    const float z = lg[i] + gumbel_from_bits(o0 ^ o1);
    if (z > bz || (z == bz && c < bi)) { bz = z; bi = c; bl = lg[i]; }
  }
#pragma unroll
  for (int d = 1; d <= 2; d <<= 1) {
    const float z2 = __shfl_xor(bz, d);
    const int i2 = __shfl_xor(bi, d);
    const float l2 = __shfl_xor(bl, d);
    if (z2 > bz || (z2 == bz && i2 < bi)) { bz = z2; bi = i2; bl = l2; }
  }
  sOut = bi;
  lpOut = (bl - m) - lse;
}

// ---------------- kernel A: packed precompute ----------------
// Gate-interleaved j' = unit*4 + gate (gate order i,f,g,o; torch j = gate*64+unit)
// embedWi[v][j'] = b_ih[j] + b_hh[j] + sum_k embed[v][k]*W_ih[j][k]   (fp32)
// Wsp[(s*256 + j')*64 + k] = s-th bf16 split of W_hh[j][k]  (exact 3-way split)
__global__ __launch_bounds__(256) void k_prep(
    const float* __restrict__ embed, const float* __restrict__ W_ih,
    const float* __restrict__ W_hh, const float* __restrict__ b_ih,
    const float* __restrict__ b_hh, float* __restrict__ embedWi,
    unsigned short* __restrict__ Wsp) {
  if (blockIdx.x >= NV) {
    int idx = (blockIdx.x - NV) * 256 + threadIdx.x;  // 0..49151
    int s = idx >> 14;
    int rem = idx & 16383;
    int jp = rem >> 6, k = rem & 63;
    int j = (jp & 3) * 64 + (jp >> 2);
    float w = W_hh[j * 64 + k];
    float f1, f2, f3;
    unsigned short b1 = bfbits(w, f1);
    unsigned short b2 = bfbits(w - f1, f2);
    unsigned short b3 = bfbits(w - f1 - f2, f3);
    Wsp[idx] = (s == 0) ? b1 : (s == 1) ? b2 : b3;
    return;
  }
  __shared__ float er[64];
  int v = blockIdx.x;
  if (threadIdx.x < 64) er[threadIdx.x] = embed[v * 64 + threadIdx.x];
  __syncthreads();
  int jp = threadIdx.x;
  int j = (jp & 3) * 64 + (jp >> 2);
  float a = b_ih[j] + b_hh[j];
#pragma unroll
  for (int k = 0; k < 64; ++k) a = fmaf(W_ih[j * 64 + k], er[k], a);
  embedWi[v * 256 + jp] = a;
}

// ---------------- kernel B: LSTM via MFMA, exact 3-way bf16 split ----------
// 256 WGs x 512 thr (1 WG/CU, 2 waves/SIMD). WG = 128 rows x 256 j'.
// GEMM: D[j'][r] = sum_k W[j'][k] h[r][k]. A = W-splits (STATIC: 24 frags
// resident in 96 VGPRs -> zero per-step weight traffic, killing r1-r7's LDS
// delivery wall). B = h^T as bf16 splits in LDS, chunk layout
// [rtg][q][n]*16B: consecutive 8-lane groups hit distinct bank-columns.
// C layout (m89): col=lane&15=row(batch), row=quad*4+reg=j'. Gate-interleaved
// j' => reg 0..3 = i,f,g,o of unit (tile*4+quad): activations + c fully
// in-register, 1 barrier/step. Products (8 of 9, small->large; drop lo*lo):
// error = fp32-rounding class (r1-level, no sample flips).
__global__ __launch_bounds__(512, 2) void k_lstm(
    const int* __restrict__ inst0, const int* __restrict__ inst1,
    const float* __restrict__ embedWi, const unsigned short* __restrict__ Wsp,
    float* __restrict__ hT) {
  extern __shared__ char smc[];
  // h bufs: 2 x 3 splits x 16384 B; ids at 98304
  int* idsb = (int*)(smc + 98304);

  const int tid = threadIdx.x;
  const int lane = tid & 63;
  const int wave = tid >> 6;      // 0..7
  const int wgj = wave >> 1;      // j'-quarter
  const int wrh = wave & 1;       // row half
  const int n15 = lane & 15;
  const int quad = lane >> 4;
  const int blk = blockIdx.x;
  const int rowbase = blk * 128;
  const int rb = rowbase & (NB - 1);
  const int* __restrict__ inst = (blk < 128) ? inst0 : inst1;

  // static A-frags: afr[jt][kc][s], element i = W_s[j'][kc*32+quad*8+i]
  bf16x8 afr[4][2][3];
#pragma unroll
  for (int jt = 0; jt < 4; ++jt) {
    const int jrow = (wgj * 4 + jt) * 16 + n15;
#pragma unroll
    for (int kc = 0; kc < 2; ++kc)
#pragma unroll
      for (int s = 0; s < 3; ++s)
        afr[jt][kc][s] =
            *(const bf16x8*)(Wsp + ((s * 256 + jrow) * 64 + kc * 32 + quad * 8));
  }

  for (int i = tid; i < 12288; i += 512) ((float*)smc)[i] = 0.f;  // zero buf 0
  if (tid < 128) idsb[tid] = inst[(rb + tid) * NSEQ];

  float cst[16];
#pragma unroll
  for (int i = 0; i < 16; ++i) cst[i] = 0.f;

  __syncthreads();

#pragma unroll 1
  for (int t = 0; t < NSEQ; ++t) {
    const char* __restrict__ hbr = smc + (t & 1) * 49152;
    char* __restrict__ hbw = smc + (((t & 1) ^ 1)) * 49152;

    int vv[4];
#pragma unroll
    for (int rt = 0; rt < 4; ++rt)
      vv[rt] = idsb[(t & 1) * 128 + wrh * 64 + rt * 16 + n15];
    if (tid < 128 && t + 1 < NSEQ)
      idsb[((t + 1) & 1) * 128 + tid] = inst[(rb + tid) * NSEQ + t + 1];

    f32x4 C[4][4];
#pragma unroll
    for (int jt = 0; jt < 4; ++jt)
#pragma unroll
      for (int rt = 0; rt < 4; ++rt) C[jt][rt] = (f32x4){0.f, 0.f, 0.f, 0.f};

#pragma unroll
    for (int rt = 0; rt < 4; ++rt) {
      const int rtg = wrh * 4 + rt;
      bf16x8 bfr[2][3];
#pragma unroll
      for (int kc = 0; kc < 2; ++kc)
#pragma unroll
        for (int s = 0; s < 3; ++s)
          bfr[kc][s] = *(const bf16x8*)(hbr + s * 16384 + rtg * 2048 +
                                        (kc * 4 + quad) * 256 + n15 * 16);
#pragma unroll
      for (int jt = 0; jt < 4; ++jt) {
#pragma unroll
        for (int kc = 0; kc < 2; ++kc) {
          f32x4 acc = C[jt][rt];
          acc = __builtin_amdgcn_mfma_f32_16x16x32_bf16(afr[jt][kc][1], bfr[kc][2], acc, 0, 0, 0);
          acc = __builtin_amdgcn_mfma_f32_16x16x32_bf16(afr[jt][kc][2], bfr[kc][1], acc, 0, 0, 0);
          acc = __builtin_amdgcn_mfma_f32_16x16x32_bf16(afr[jt][kc][0], bfr[kc][2], acc, 0, 0, 0);
          acc = __builtin_amdgcn_mfma_f32_16x16x32_bf16(afr[jt][kc][2], bfr[kc][0], acc, 0, 0, 0);
          acc = __builtin_amdgcn_mfma_f32_16x16x32_bf16(afr[jt][kc][1], bfr[kc][1], acc, 0, 0, 0);
          acc = __builtin_amdgcn_mfma_f32_16x16x32_bf16(afr[jt][kc][0], bfr[kc][1], acc, 0, 0, 0);
          acc = __builtin_amdgcn_mfma_f32_16x16x32_bf16(afr[jt][kc][1], bfr[kc][0], acc, 0, 0, 0);
          acc = __builtin_amdgcn_mfma_f32_16x16x32_bf16(afr[jt][kc][0], bfr[kc][0], acc, 0, 0, 0);
          C[jt][rt] = acc;
        }
      }
    }

    // epilogue: es ping-pong per jt (32 regs, not 64 -> no spill)
    const bool last = (t == NSEQ - 1);
    float4 esA[4], esB[4];
#pragma unroll
    for (int rt = 0; rt < 4; ++rt)
      esA[rt] = *(const float4*)(embedWi + vv[rt] * 256 + (wgj * 16 + 0 * 4 + quad) * 4);
#pragma unroll
    for (int jt = 0; jt < 4; ++jt) {
      if (jt < 3) {
#pragma unroll
        for (int rt = 0; rt < 4; ++rt)
          esB[rt] = *(const float4*)(embedWi + vv[rt] * 256 +
                                     (wgj * 16 + (jt + 1) * 4 + quad) * 4);
      }
      const int u = wgj * 16 + jt * 4 + quad;
#pragma unroll
      for (int rt = 0; rt < 4; ++rt) {
        const int r = wrh * 64 + rt * 16 + n15;
        const float gi = C[jt][rt].x + esA[rt].x;
        const float gf = C[jt][rt].y + esA[rt].y;
        const float gg = C[jt][rt].z + esA[rt].z;
        const float go = C[jt][rt].w + esA[rt].w;
        const float ci = sigm(gf) * cst[jt * 4 + rt] + sigm(gi) * tanh_(gg);
        cst[jt * 4 + rt] = ci;
        const float h = sigm(go) * tanh_(ci);
        float f1, f2, f3;
        const unsigned short b1 = bfbits(h, f1);
        const unsigned short b2 = bfbits(h - f1, f2);
        const unsigned short b3 = bfbits(h - f1 - f2, f3);
        const int coff = (r >> 4) * 2048 + (u >> 3) * 256 + (r & 15) * 16 + (u & 7) * 2;
        *(unsigned short*)(hbw + 0 * 16384 + coff) = b1;
        *(unsigned short*)(hbw + 1 * 16384 + coff) = b2;
        *(unsigned short*)(hbw + 2 * 16384 + coff) = b3;
        if (last) hT[u * NROWS + rowbase + r] = h;
      }
#pragma unroll
      for (int rt = 0; rt < 4; ++rt) esA[rt] = esB[rt];
    }
    __syncthreads();
  }
}

// ---------------- kernel C: heads, 4-lane team per row (bit-exact r3+) -----
__global__ __launch_bounds__(256) void k_heads(
    const int* __restrict__ canvas0, const int* __restrict__ canvas1,
    const int* __restrict__ ref,
    const float* __restrict__ Wc, const float* __restrict__ bc,
    const float* __restrict__ Ws, const float* __restrict__ bs,
    const float* __restrict__ Wl, const float* __restrict__ bl,
    const float* __restrict__ Wr1, const float* __restrict__ br1,
    const float* __restrict__ Wr2, const float* __restrict__ br2,
    const float* __restrict__ Wp, const float* __restrict__ bp,
    const float* __restrict__ hT, float* __restrict__ out) {
  const int tid = threadIdx.x;
  const int g = tid & 3;
  const int s = blockIdx.x & 1;
  const int b = (blockIdx.x >> 1) * 64 + (tid >> 2);
  const float NEG = -__builtin_inff();

  uint32_t kk0[7], kk1[7];
#pragma unroll
  for (int i = 0; i < 7; ++i) {
    uint32_t o0, o1; tf2x32(0u, 42u, 0u, (uint32_t)i, o0, o1);
    kk0[i] = o0; kk1[i] = o1;
  }

  float h[64];
#pragma unroll
  for (int u = 0; u < 64; ++u) h[u] = hT[u * NROWS + s * NB + b];

  float lgc[1], lgs[1];
  lgc[0] = (g < 3) ? (bc[g] + dot64(Wc + g * 64, h)) : NEG;
  lgs[0] = (g < 3) ? (bs[g] + dot64(Ws + g * 64, h)) : NEG;

  if (s == 0) {
    int cs0, ss0, loc0; float clp0, slp0, llp0;
    samp_team<1>(lgc, g, 3, kk0[0], kk1[0], b, cs0, clp0);
    samp_team<1>(lgs, g, 3, kk0[1], kk1[1], b, ss0, slp0);
    float lgl[7];
#pragma unroll
    for (int i = 0; i < 7; ++i) {
      const int cc = g + 4 * i;
      lgl[i] = (cc < 25) ? (bl[cc] + dot64(Wl + cc * 64, h)) : NEG;
    }
    samp_team<7>(lgl, g, 25, kk0[2], kk1[2], b, loc0, llp0);

    if (g == 0) {
      const int p0 = min(max(loc0, 0), 24);
      const int4 pt = ((const int4*)(canvas1 + b * 100))[p0];
      const bool ok0 = (loc0 >= 0) && (loc0 < 25) && (pt.x + pt.y + pt.z + pt.w >= 0);
      const float loc_r0 = ok0 ? 1.f : -1.f;
      const float col_r0 = ok0 ? ((cs0 == pt.x) ? 1.f : -1.f) : 0.f;
      out[0 * NB + b] = clp0;
      out[1 * NB + b] = slp0;
      out[2 * NB + b] = llp0;
      out[7 * NB + b] = loc_r0;
      out[8 * NB + b] = col_r0;
      out[9 * NB + b] = loc_r0;
    }
  } else {
    int cs1, ss1, ls1; float clp1, slp1, llp1;
    samp_team<1>(lgc, g, 3, kk0[3], kk1[3], b, cs1, clp1);
    samp_team<1>(lgs, g, 3, kk0[4], kk1[4], b, ss1, slp1);
    float lgp[2];
#pragma unroll
    for (int i = 0; i < 2; ++i) {
      const int cc = g + 4 * i;
      lgp[i] = bp[cc] + dot64(Wp + cc * 64, h);
    }
    samp_team<2>(lgp, g, 8, kk0[5], kk1[5], b, ls1, llp1);

    float uv8[8], w64[8], w65[8], w66[8], w67[8], wr2[8];
#pragma unroll
    for (int i = 0; i < 8; ++i) {
      const int j = g + 4 * i;
      uv8[i] = br1[j] + dot64(Wr1 + j * 68, h);
      const float* wr = Wr1 + j * 68 + 64;
      w64[i] = wr[0]; w65[i] = wr[1]; w66[i] = wr[2]; w67[i] = wr[3];
      wr2[i] = Wr2[j];
    }
    float lgA[7];
#pragma unroll
    for (int i = 0; i < 7; ++i) lgA[i] = NEG;
    const float b2 = br2[0];
#pragma unroll
    for (int p = 0; p < 25; ++p) {
      const int4 c4 = ((const int4*)(canvas0 + b * 100))[p];
      const float f0 = (float)c4.x, f1 = (float)c4.y;
      const float f2 = (float)c4.z, f3 = (float)c4.w;
      float part = 0.f;
#pragma unroll
      for (int i = 0; i < 8; ++i) {
        float hj = uv8[i];
        hj = fmaf(w64[i], f0, hj);
        hj = fmaf(w65[i], f1, hj);
        hj = fmaf(w66[i], f2, hj);
        hj = fmaf(w67[i], f3, hj);
        part = fmaf(wr2[i], fmaxf(hj, 0.f), part);
      }
      part += __shfl_xor(part, 1);
      part += __shfl_xor(part, 2);
      const float ap = b2 + part;
      if ((p & 3) == g) lgA[p >> 2] = ap;
    }
    int att_s; float alp1;
    samp_team<7>(lgA, g, 25, kk0[6], kk1[6], b, att_s, alp1);

    if (g == 0) {
      const int4 r4 = ((const int4*)(canvas0 + b * 100))[att_s];
      const int4 rr = *(const int4*)(ref + b * 4);
      const bool match = (r4.x == rr.x) && (r4.y == rr.y) &&
                         (r4.z == rr.z) && (r4.w == rr.w);
      const float att_reward = match ? 1.f : -1.f;
      const int ox = (int)((0x22001120u >> (ls1 * 4)) & 0xFu) - 1;
      const int oy = (int)((0x20200211u >> (ls1 * 4)) & 0xFu) - 1;
      const int loc1 = (r4.z + ox) * 5 + (r4.w + oy);
      const int p1 = min(max(loc1, 0), 24);
      const int4 q4 = ((const int4*)(canvas1 + b * 100))[p1];
      const bool ok1 = (loc1 >= 0) && (loc1 < 25) && (q4.x + q4.y + q4.z + q4.w >= 0);
      const float loc_r1 = ok1 ? 1.f : -1.f;
      const float col_r1 = ok1 ? ((cs1 == q4.x) ? 1.f : -1.f) : 0.f;
      out[3 * NB + b]  = clp1;
      out[4 * NB + b]  = slp1;
      out[5 * NB + b]  = llp1;
      out[6 * NB + b]  = alp1;
      out[10 * NB + b] = loc_r1;
      out[11 * NB + b] = col_r1;
      out[12 * NB + b] = loc_r1;
      out[13 * NB + b] = att_reward;
    }
  }
}

extern "C" void kernel_launch(void* const* d_in, const int* in_sizes, int n_in,
                              void* d_out, int out_size, void* d_ws, size_t ws_size,
                              hipStream_t stream) {
  const int* inst0 = (const int*)d_in[0];
  const int* inst1 = (const int*)d_in[1];
  const int* canvas0 = (const int*)d_in[2];
  const int* canvas1 = (const int*)d_in[3];
  const int* ref = (const int*)d_in[4];
  const float* embed = (const float*)d_in[5];
  const float* W_ih = (const float*)d_in[6];
  const float* W_hh = (const float*)d_in[7];
  const float* b_ih = (const float*)d_in[8];
  const float* b_hh = (const float*)d_in[9];
  const float* Wc = (const float*)d_in[10];
  const float* bc = (const float*)d_in[11];
  const float* Ws = (const float*)d_in[12];
  const float* bs = (const float*)d_in[13];
  const float* Wl = (const float*)d_in[14];
  const float* bl = (const float*)d_in[15];
  const float* Wr1 = (const float*)d_in[16];
  const float* br1 = (const float*)d_in[17];
  const float* Wr2 = (const float*)d_in[18];
  const float* br2 = (const float*)d_in[19];
  const float* Wp = (const float*)d_in[20];
  const float* bp = (const float*)d_in[21];

  float* ws = (float*)d_ws;
  float* embedWi = ws;                               // 1001*256 fp32
  unsigned short* Wsp = (unsigned short*)(ws + NV * 256);  // 3*256*64 bf16
  float* hT = ws + NV * 256 + 24576;                 // 64*32768 fp32
  float* out = (float*)d_out;

  (void)hipFuncSetAttribute((const void*)k_lstm,
                            hipFuncAttributeMaxDynamicSharedMemorySize, 163840);

  k_prep<<<NV + 192, 256, 0, stream>>>(embed, W_ih, W_hh, b_ih, b_hh, embedWi, Wsp);
  k_lstm<<<256, 512, 99328, stream>>>(inst0, inst1, embedWi, Wsp, hT);
  k_heads<<<512, 256, 0, stream>>>(canvas0, canvas1, ref, Wc, bc, Ws, bs,
                                   Wl, bl, Wr1, br1, Wr2, br2, Wp, bp, hT, out);
}